// Round 1
// baseline (80.515 us; speedup 1.0000x reference)
//
#include <hip/hip_runtime.h>

#define HW      256
#define TILE    32
#define HALO    3
#define PSIDE   (TILE + 2*HALO)   // 38
#define LSTRIDE (PSIDE + 2)       // 40 floats -> lane-pair bank aliasing only (free)

__global__ __launch_bounds__(256) void census_loss_kernel(
    const float* __restrict__ x, const float* __restrict__ y,
    float* __restrict__ out)
{
    __shared__ float sgx[PSIDE][LSTRIDE];
    __shared__ float sgy[PSIDE][LSTRIDE];

    const int b   = blockIdx.z;
    const int ti0 = blockIdx.y * TILE;   // tile row origin
    const int tj0 = blockIdx.x * TILE;   // tile col origin

    const float* xb = x + (size_t)b * 3 * HW * HW;
    const float* yb = y + (size_t)b * 3 * HW * HW;

    const int tid = threadIdx.x;
    const float third = 1.0f / 3.0f;

    // ---- stage grayscale halo (38x38) for both images into LDS ----
    for (int li = tid; li < PSIDE * PSIDE; li += 256) {
        int r = li / PSIDE;
        int c = li - r * PSIDE;
        int gi = ti0 + r - HALO;
        int gj = tj0 + c - HALO;
        float gx = 0.0f, gy = 0.0f;
        if ((unsigned)gi < HW && (unsigned)gj < HW) {
            int o = gi * HW + gj;
            gx = (xb[o] + xb[o + HW*HW] + xb[o + 2*HW*HW]) * third;
            gy = (yb[o] + yb[o + HW*HW] + yb[o + 2*HW*HW]) * third;
        }
        sgx[r][c] = gx;
        sgy[r][c] = gy;
    }
    __syncthreads();

    // ---- per-pixel 7x7 census compare; each thread does 4 rows ----
    const int tx  = tid & 31;   // local col 0..31
    const int tyb = tid >> 5;   // 0..7
    float acc = 0.0f;

    #pragma unroll
    for (int k = 0; k < 4; ++k) {
        const int ly = tyb + 8 * k;        // local row 0..31
        const int gi = ti0 + ly;
        const int gj = tj0 + tx;
        // interior mask: pad=3 border contributes 0
        if (gi >= HALO && gi < HW - HALO && gj >= HALO && gj < HW - HALO) {
            const float cx = sgx[ly + HALO][tx + HALO];
            const float cy = sgy[ly + HALO][tx + HALO];
            #pragma unroll
            for (int dy = 0; dy < 7; ++dy) {
                #pragma unroll
                for (int dx = 0; dx < 7; ++dx) {
                    float nx = sgx[ly + dy][tx + dx];
                    float ny = sgy[ly + dy][tx + dx];
                    float ux = nx - cx;
                    float uy = ny - cy;
                    // f(t) = t / sqrt(0.81 + t^2)
                    float fx = ux * __builtin_amdgcn_rsqf(0.81f + ux * ux);
                    float fy = uy * __builtin_amdgcn_rsqf(0.81f + uy * uy);
                    float d  = fx - fy;
                    float d2 = d * d;
                    acc += d2 * __builtin_amdgcn_rcpf(0.1f + d2);
                }
            }
        }
    }

    // ---- reduce: wave shuffle -> LDS -> one atomic per block ----
    #pragma unroll
    for (int off = 32; off > 0; off >>= 1)
        acc += __shfl_down(acc, off, 64);

    __shared__ float wsum[4];
    const int lane = tid & 63;
    const int wid  = tid >> 6;
    if (lane == 0) wsum[wid] = acc;
    __syncthreads();
    if (tid == 0) {
        float s = wsum[0] + wsum[1] + wsum[2] + wsum[3];
        // scale: mean over 49 offsets, then mean over B*1*H*W
        const float scale = 1.0f / (49.0f * 8.0f * 256.0f * 256.0f);
        atomicAdd(out, s * scale);
    }
}

extern "C" void kernel_launch(void* const* d_in, const int* in_sizes, int n_in,
                              void* d_out, int out_size, void* d_ws, size_t ws_size,
                              hipStream_t stream) {
    const float* x = (const float*)d_in[0];
    const float* y = (const float*)d_in[1];
    float* out = (float*)d_out;

    // d_out is poisoned to 0xAA before every timed launch -> zero it ourselves
    hipMemsetAsync(out, 0, sizeof(float) * out_size, stream);

    dim3 grid(HW / TILE, HW / TILE, 8);   // 8 x 8 tiles x 8 batches = 512 blocks
    dim3 block(256);
    census_loss_kernel<<<grid, block, 0, stream>>>(x, y, out);
}